// Round 14
// baseline (142.192 us; speedup 1.0000x reference)
//
#include <hip/hip_runtime.h>
#include <hip/hip_cooperative_groups.h>
#include <math.h>

namespace cg = cooperative_groups;

#define N_NODES 10000
#define N_EDGES 160000
#define D 256
#define KDIM 512   // 2*D
#define CAP 64     // fixed CSR capacity per node (P(deg>64) ~ 1e-22 for Poisson(16))
#define SPLIT 5000 // col partition for L2-friendly two-sweep gathers
#define GRID 512
#define BLK 256

typedef short bf16x8 __attribute__((ext_vector_type(8)));
typedef float f32x4 __attribute__((ext_vector_type(4)));
typedef unsigned short ushort_t;

__device__ __forceinline__ ushort_t f2bf(float f) {
    unsigned u = __builtin_bit_cast(unsigned, f);
    unsigned r = (u + 0x7fffu + ((u >> 16) & 1u)) >> 16;
    return (ushort_t)r;
}
__device__ __forceinline__ float bf2f(ushort_t u) {
    unsigned v = ((unsigned)u) << 16;
    return __builtin_bit_cast(float, v);
}

// ---------------- cooperative prep: {zero|prepW|castX} -> grid.sync -> fill ----------------
__global__ __launch_bounds__(BLK, 4) void k_prep(
    const int* __restrict__ row, const int* __restrict__ colv,
    int* __restrict__ cursors /*curLo|curHi*/, int* __restrict__ csr_col,
    const float* __restrict__ Wr, const float* __restrict__ Wn,
    ushort_t* __restrict__ Wb, const float* __restrict__ X,
    ushort_t* __restrict__ A)
{
    cg::grid_group grid = cg::this_grid();
    __shared__ float tile[32][33];
    const int b = blockIdx.x;
    const int t = threadIdx.x;
    const int lane = t & 63;
    const int wv = t >> 6;

    // Phase A1: zero cursors (20000 ints)
    {
        int i = b * BLK + t;
        if (i < 2 * N_NODES) cursors[i] = 0;
    }
    // Phase A2: W transpose+cast (blocks 0..127)
    if (b < 128) {
        int k0 = (b & 15) * 32, n0 = (b >> 4) * 32;
        {
            int r = t >> 3, c4 = t & 7;
            int k = k0 + r;
            const float* src = (k < D) ? (Wr + (size_t)k * D + n0 + c4 * 4)
                                       : (Wn + (size_t)(k - D) * D + n0 + c4 * 4);
            float4 v = *(const float4*)src;
            tile[r][c4 * 4 + 0] = v.x; tile[r][c4 * 4 + 1] = v.y;
            tile[r][c4 * 4 + 2] = v.z; tile[r][c4 * 4 + 3] = v.w;
        }
        __syncthreads();
        {
            int n = t >> 3, kq = t & 7;
            ushort4 o = make_ushort4(f2bf(tile[kq * 4 + 0][n]), f2bf(tile[kq * 4 + 1][n]),
                                     f2bf(tile[kq * 4 + 2][n]), f2bf(tile[kq * 4 + 3][n]));
            *(ushort4*)(Wb + (size_t)(n0 + n) * KDIM + k0 + kq * 4) = o;
        }
    }
    // Phase A3: X -> bf16 into A[:,0:256] (grid-stride)
    for (int nb = b; nb < 2500; nb += GRID) {
        int node = nb * 4 + wv;   // < 10000 always
        float4 v = *(const float4*)(X + (size_t)node * D + lane * 4);
        ushort4 o = make_ushort4(f2bf(v.x), f2bf(v.y), f2bf(v.z), f2bf(v.w));
        *(ushort4*)(A + (size_t)node * KDIM + lane * 4) = o;
    }
    grid.sync();

    // Phase B: fill fixed-stride CSR, two-sweep partition
    for (int i = b * BLK + t; i < N_EDGES; i += GRID * BLK) {
        int r = row[i], c = colv[i];
        if (c < SPLIT) {
            int p = atomicAdd(&cursors[r], 1);
            csr_col[r * CAP + p] = c;
        } else {
            int p = atomicAdd(&cursors[N_NODES + r], 1);
            csr_col[r * CAP + CAP - 1 - p] = c;
        }
    }
}

// ---------------- neighbor mean (two-sweep bf16 gather, unroll 4) ----------------
__global__ void k_mean(const int* __restrict__ curLo, const int* __restrict__ curHi,
                       const int* __restrict__ csr_col, ushort_t* __restrict__ A) {
    int node = blockIdx.x * 4 + (threadIdx.x >> 6);
    int lane = threadIdx.x & 63;
    if (node >= N_NODES) return;
    int s0 = node * CAP;
    int nlo = curLo[node], nhi = curHi[node];
    float ax = 0.f, ay = 0.f, az = 0.f, aw = 0.f;
    #pragma unroll 1
    for (int half = 0; half < 2; ++half) {
        int s = half ? (s0 + CAP - nhi) : s0;
        int t = half ? (s0 + CAP) : (s0 + nlo);
        int e = s;
        for (; e + 4 <= t; e += 4) {
            int j0 = csr_col[e], j1 = csr_col[e + 1], j2 = csr_col[e + 2], j3 = csr_col[e + 3];
            ushort4 v0 = *(const ushort4*)(A + (size_t)j0 * KDIM + lane * 4);
            ushort4 v1 = *(const ushort4*)(A + (size_t)j1 * KDIM + lane * 4);
            ushort4 v2 = *(const ushort4*)(A + (size_t)j2 * KDIM + lane * 4);
            ushort4 v3 = *(const ushort4*)(A + (size_t)j3 * KDIM + lane * 4);
            ax += bf2f(v0.x) + bf2f(v1.x) + bf2f(v2.x) + bf2f(v3.x);
            ay += bf2f(v0.y) + bf2f(v1.y) + bf2f(v2.y) + bf2f(v3.y);
            az += bf2f(v0.z) + bf2f(v1.z) + bf2f(v2.z) + bf2f(v3.z);
            aw += bf2f(v0.w) + bf2f(v1.w) + bf2f(v2.w) + bf2f(v3.w);
        }
        for (; e < t; ++e) {
            int j = csr_col[e];
            ushort4 v = *(const ushort4*)(A + (size_t)j * KDIM + lane * 4);
            ax += bf2f(v.x); ay += bf2f(v.y); az += bf2f(v.z); aw += bf2f(v.w);
        }
    }
    int deg = nlo + nhi;
    float inv = 1.f / (float)(deg > 1 ? deg : 1);
    ushort4 o = make_ushort4(f2bf(ax * inv), f2bf(ay * inv), f2bf(az * inv), f2bf(aw * inv));
    *(ushort4*)(A + (size_t)node * KDIM + D + lane * 4) = o;   // re-read by GEMM: keep cached
}

// ---------------- MFMA GEMM: H(bf16) = relu(A @ Wb^T + b) ----------------
#define BM 64
#define BN 128
#define BK 32
#define LDK 40   // padded LDS k-stride (ushorts)

__global__ __launch_bounds__(256) void k_gemm(
    const ushort_t* __restrict__ A, const ushort_t* __restrict__ Wb,
    const float* __restrict__ bias, ushort_t* __restrict__ H) {
    __shared__ ushort_t As[BM][LDK];
    __shared__ ushort_t Bs[BN][LDK];

    int tid = threadIdx.x;
    int lane = tid & 63;
    int wave = tid >> 6;
    int wm = wave >> 1;   // 0..1: 32-row half
    int wn = wave & 1;    // 0..1: 64-col half
    int row0 = blockIdx.x * BM;
    int col0 = blockIdx.y * BN;

    f32x4 acc[2][4];
    #pragma unroll
    for (int i = 0; i < 2; ++i)
        #pragma unroll
        for (int j = 0; j < 4; ++j)
            acc[i][j] = (f32x4){0.f, 0.f, 0.f, 0.f};

    int r_a = tid >> 2;
    int kq = tid & 3;

    for (int kk = 0; kk < KDIM; kk += BK) {
        int ga = row0 + r_a; if (ga >= N_NODES) ga = N_NODES - 1;
        ushort4 a0 = *(const ushort4*)(A + (size_t)ga * KDIM + kk + kq * 8);
        ushort4 a1 = *(const ushort4*)(A + (size_t)ga * KDIM + kk + kq * 8 + 4);
        ushort4 b0 = *(const ushort4*)(Wb + (size_t)(col0 + r_a) * KDIM + kk + kq * 8);
        ushort4 b1 = *(const ushort4*)(Wb + (size_t)(col0 + r_a) * KDIM + kk + kq * 8 + 4);
        ushort4 b2 = *(const ushort4*)(Wb + (size_t)(col0 + r_a + 64) * KDIM + kk + kq * 8);
        ushort4 b3 = *(const ushort4*)(Wb + (size_t)(col0 + r_a + 64) * KDIM + kk + kq * 8 + 4);

        __syncthreads();
        *(ushort4*)&As[r_a][kq * 8]          = a0;
        *(ushort4*)&As[r_a][kq * 8 + 4]      = a1;
        *(ushort4*)&Bs[r_a][kq * 8]          = b0;
        *(ushort4*)&Bs[r_a][kq * 8 + 4]      = b1;
        *(ushort4*)&Bs[r_a + 64][kq * 8]     = b2;
        *(ushort4*)&Bs[r_a + 64][kq * 8 + 4] = b3;
        __syncthreads();

        int fr = lane & 15, fg = (lane >> 4) * 8;
        bf16x8 aF[2], bF[4];
        #pragma unroll
        for (int mf = 0; mf < 2; ++mf)
            aF[mf] = *(const bf16x8*)&As[wm * 32 + mf * 16 + fr][fg];
        #pragma unroll
        for (int nf = 0; nf < 4; ++nf)
            bF[nf] = *(const bf16x8*)&Bs[wn * 64 + nf * 16 + fr][fg];
        #pragma unroll
        for (int mf = 0; mf < 2; ++mf)
            #pragma unroll
            for (int nf = 0; nf < 4; ++nf)
                acc[mf][nf] = __builtin_amdgcn_mfma_f32_16x16x32_bf16(
                    aF[mf], bF[nf], acc[mf][nf], 0, 0, 0);
    }

    int fc = lane & 15, frow = (lane >> 4) * 4;
    #pragma unroll
    for (int nf = 0; nf < 4; ++nf) {
        int c = col0 + wn * 64 + nf * 16 + fc;
        float bc = bias[c];
        #pragma unroll
        for (int mf = 0; mf < 2; ++mf) {
            #pragma unroll
            for (int q = 0; q < 4; ++q) {
                int r = row0 + wm * 32 + mf * 16 + frow + q;
                if (r < N_NODES) {
                    float h = acc[mf][nf][q] + bc;
                    H[(size_t)r * D + c] = f2bf(h > 0.f ? h : 0.f);
                }
            }
        }
    }
}

// ---------------- edge diffs (two-sweep bf16 gather) -> scatter-mean -> tanh ----------------
__global__ void k_out(const ushort_t* __restrict__ H,
                      const int* __restrict__ curLo, const int* __restrict__ curHi,
                      const int* __restrict__ csr_col,
                      float* __restrict__ out) {
    int node = blockIdx.x * 4 + (threadIdx.x >> 6);
    int lane = threadIdx.x & 63;
    if (node >= N_NODES) return;
    ushort4 hb = *(const ushort4*)(H + (size_t)node * D + lane * 4);
    float hx = bf2f(hb.x), hy = bf2f(hb.y), hz = bf2f(hb.z), hw = bf2f(hb.w);
    int s0 = node * CAP;
    int nlo = curLo[node], nhi = curHi[node];
    float ax = 0.f, ay = 0.f, az = 0.f, aw = 0.f;
    #pragma unroll 1
    for (int half = 0; half < 2; ++half) {
        int s = half ? (s0 + CAP - nhi) : s0;
        int t = half ? (s0 + CAP) : (s0 + nlo);
        int e = s;
        for (; e + 4 <= t; e += 4) {
            int j0 = csr_col[e], j1 = csr_col[e + 1], j2 = csr_col[e + 2], j3 = csr_col[e + 3];
            ushort4 v0 = *(const ushort4*)(H + (size_t)j0 * D + lane * 4);
            ushort4 v1 = *(const ushort4*)(H + (size_t)j1 * D + lane * 4);
            ushort4 v2 = *(const ushort4*)(H + (size_t)j2 * D + lane * 4);
            ushort4 v3 = *(const ushort4*)(H + (size_t)j3 * D + lane * 4);
            float d;
            d = hx - bf2f(v0.x); ax += d * d;  d = hy - bf2f(v0.y); ay += d * d;
            d = hz - bf2f(v0.z); az += d * d;  d = hw - bf2f(v0.w); aw += d * d;
            d = hx - bf2f(v1.x); ax += d * d;  d = hy - bf2f(v1.y); ay += d * d;
            d = hz - bf2f(v1.z); az += d * d;  d = hw - bf2f(v1.w); aw += d * d;
            d = hx - bf2f(v2.x); ax += d * d;  d = hy - bf2f(v2.y); ay += d * d;
            d = hz - bf2f(v2.z); az += d * d;  d = hw - bf2f(v2.w); aw += d * d;
            d = hx - bf2f(v3.x); ax += d * d;  d = hy - bf2f(v3.y); ay += d * d;
            d = hz - bf2f(v3.z); az += d * d;  d = hw - bf2f(v3.w); aw += d * d;
        }
        for (; e < t; ++e) {
            int j = csr_col[e];
            ushort4 v = *(const ushort4*)(H + (size_t)j * D + lane * 4);
            float d;
            d = hx - bf2f(v.x); ax += d * d;  d = hy - bf2f(v.y); ay += d * d;
            d = hz - bf2f(v.z); az += d * d;  d = hw - bf2f(v.w); aw += d * d;
        }
    }
    int deg = nlo + nhi;
    float inv = 1.f / (float)(deg > 1 ? deg : 1);
    f32x4 o;
    o[0] = tanhf(ax * inv); o[1] = tanhf(ay * inv);
    o[2] = tanhf(az * inv); o[3] = tanhf(aw * inv);
    __builtin_nontemporal_store(o, (f32x4*)(out + (size_t)node * D + lane * 4));
}

// ---------------- launch ----------------

extern "C" void kernel_launch(void* const* d_in, const int* in_sizes, int n_in,
                              void* d_out, int out_size, void* d_ws, size_t ws_size,
                              hipStream_t stream) {
    const float* X    = (const float*)d_in[0];
    const int*   edge = (const int*)d_in[1];
    const float* Wr   = (const float*)d_in[2];
    const float* Wn   = (const float*)d_in[3];
    const float* bias = (const float*)d_in[4];
    float* out = (float*)d_out;

    char* ws = (char*)d_ws;
    size_t off = 0;
    auto alloc = [&](size_t bytes) -> void* {
        void* p = ws + off;
        off += (bytes + 255) & ~(size_t)255;
        return p;
    };
    int*      cursors = (int*)alloc(sizeof(int) * 2 * N_NODES);   // curLo | curHi
    int*      csr_col = (int*)alloc(sizeof(int) * N_NODES * CAP);
    ushort_t* A       = (ushort_t*)alloc(sizeof(ushort_t) * (size_t)N_NODES * KDIM);
    ushort_t* Wb      = (ushort_t*)alloc(sizeof(ushort_t) * (size_t)D * KDIM);
    ushort_t* H       = (ushort_t*)alloc(sizeof(ushort_t) * (size_t)N_NODES * D);

    int* curLo = cursors;
    int* curHi = cursors + N_NODES;
    const int* row  = edge;
    const int* colv = edge + N_EDGES;

    void* args[] = {
        (void*)&row, (void*)&colv, (void*)&cursors, (void*)&csr_col,
        (void*)&Wr, (void*)&Wn, (void*)&Wb, (void*)&X, (void*)&A
    };
    hipLaunchCooperativeKernel((void*)k_prep, dim3(GRID), dim3(BLK), args, 0, stream);

    k_mean<<<2500, 256, 0, stream>>>(curLo, curHi, csr_col, A);

    dim3 ggrid((N_NODES + BM - 1) / BM, D / BN);
    k_gemm<<<ggrid, 256, 0, stream>>>(A, Wb, bias, H);

    k_out<<<2500, 256, 0, stream>>>(H, curLo, curHi, csr_col, out);
}

// Round 15
// 64.722 us; speedup vs baseline: 2.1970x; 2.1970x over previous
//
#include <hip/hip_runtime.h>
#include <math.h>

#define N_NODES 10000
#define N_EDGES 160000
#define D 256
#define KDIM 512   // 2*D
#define CAP 64     // fixed CSR capacity per node (P(deg>64) ~ 1e-22 for Poisson(16))
#define SPLIT 5000 // col partition for L2-friendly two-sweep gathers

typedef short bf16x8 __attribute__((ext_vector_type(8)));
typedef float f32x4 __attribute__((ext_vector_type(4)));
typedef unsigned short ushort_t;

__device__ __forceinline__ ushort_t f2bf(float f) {
    unsigned u = __builtin_bit_cast(unsigned, f);
    unsigned r = (u + 0x7fffu + ((u >> 16) & 1u)) >> 16;
    return (ushort_t)r;
}
__device__ __forceinline__ float bf2f(ushort_t u) {
    unsigned v = ((unsigned)u) << 16;
    return __builtin_bit_cast(float, v);
}

// ---------------- fused init: zero cursors | W transpose+cast | X cast ----------------
#define ZERO_BLOCKS 79     // 2*10000 ints
#define PREPW_BLOCKS 128   // 16 k-tiles x 8 n-tiles
#define CASTX_BLOCKS 2500

__global__ void k_init(int* __restrict__ cursors,
                       const float* __restrict__ Wr, const float* __restrict__ Wn,
                       ushort_t* __restrict__ Wb,
                       const float* __restrict__ X, ushort_t* __restrict__ A) {
    __shared__ float tile[32][33];
    int b = blockIdx.x;
    int t = threadIdx.x;
    if (b < ZERO_BLOCKS) {
        int i = b * 256 + t;
        if (i < 2 * N_NODES) cursors[i] = 0;
    } else if (b < ZERO_BLOCKS + PREPW_BLOCKS) {
        int wb = b - ZERO_BLOCKS;
        int k0 = (wb & 15) * 32, n0 = (wb >> 4) * 32;
        {
            int r = t >> 3, c4 = t & 7;
            int k = k0 + r;
            const float* src = (k < D) ? (Wr + (size_t)k * D + n0 + c4 * 4)
                                       : (Wn + (size_t)(k - D) * D + n0 + c4 * 4);
            float4 v = *(const float4*)src;
            tile[r][c4 * 4 + 0] = v.x; tile[r][c4 * 4 + 1] = v.y;
            tile[r][c4 * 4 + 2] = v.z; tile[r][c4 * 4 + 3] = v.w;
        }
        __syncthreads();
        {
            int n = t >> 3, kq = t & 7;
            ushort4 o = make_ushort4(f2bf(tile[kq * 4 + 0][n]), f2bf(tile[kq * 4 + 1][n]),
                                     f2bf(tile[kq * 4 + 2][n]), f2bf(tile[kq * 4 + 3][n]));
            *(ushort4*)(Wb + (size_t)(n0 + n) * KDIM + k0 + kq * 4) = o;
        }
    } else {
        int nb = b - ZERO_BLOCKS - PREPW_BLOCKS;
        int node = nb * 4 + (t >> 6), lane = t & 63;
        if (node < N_NODES) {
            float4 v = *(const float4*)(X + (size_t)node * D + lane * 4);
            ushort4 o = make_ushort4(f2bf(v.x), f2bf(v.y), f2bf(v.z), f2bf(v.w));
            *(ushort4*)(A + (size_t)node * KDIM + lane * 4) = o;
        }
    }
}

// ---------------- fill: fixed-stride CSR, two-sweep partition ----------------
__global__ void k_fill(const int* __restrict__ row, const int* __restrict__ col,
                       int* __restrict__ curLo, int* __restrict__ curHi,
                       int* __restrict__ csr_col, int e) {
    int i = blockIdx.x * blockDim.x + threadIdx.x;
    if (i < e) {
        int r = row[i], c = col[i];
        if (c < SPLIT) {
            int p = atomicAdd(&curLo[r], 1);
            csr_col[r * CAP + p] = c;
        } else {
            int p = atomicAdd(&curHi[r], 1);
            csr_col[r * CAP + CAP - 1 - p] = c;
        }
    }
}

// ---------------- neighbor mean (two-sweep bf16 gather, unroll 4) ----------------
__global__ void k_mean(const int* __restrict__ curLo, const int* __restrict__ curHi,
                       const int* __restrict__ csr_col, ushort_t* __restrict__ A) {
    int node = blockIdx.x * 4 + (threadIdx.x >> 6);
    int lane = threadIdx.x & 63;
    if (node >= N_NODES) return;
    int s0 = node * CAP;
    int nlo = curLo[node], nhi = curHi[node];
    float ax = 0.f, ay = 0.f, az = 0.f, aw = 0.f;
    #pragma unroll 1
    for (int half = 0; half < 2; ++half) {
        int s = half ? (s0 + CAP - nhi) : s0;
        int t = half ? (s0 + CAP) : (s0 + nlo);
        int e = s;
        for (; e + 4 <= t; e += 4) {
            int j0 = csr_col[e], j1 = csr_col[e + 1], j2 = csr_col[e + 2], j3 = csr_col[e + 3];
            ushort4 v0 = *(const ushort4*)(A + (size_t)j0 * KDIM + lane * 4);
            ushort4 v1 = *(const ushort4*)(A + (size_t)j1 * KDIM + lane * 4);
            ushort4 v2 = *(const ushort4*)(A + (size_t)j2 * KDIM + lane * 4);
            ushort4 v3 = *(const ushort4*)(A + (size_t)j3 * KDIM + lane * 4);
            ax += bf2f(v0.x) + bf2f(v1.x) + bf2f(v2.x) + bf2f(v3.x);
            ay += bf2f(v0.y) + bf2f(v1.y) + bf2f(v2.y) + bf2f(v3.y);
            az += bf2f(v0.z) + bf2f(v1.z) + bf2f(v2.z) + bf2f(v3.z);
            aw += bf2f(v0.w) + bf2f(v1.w) + bf2f(v2.w) + bf2f(v3.w);
        }
        for (; e < t; ++e) {
            int j = csr_col[e];
            ushort4 v = *(const ushort4*)(A + (size_t)j * KDIM + lane * 4);
            ax += bf2f(v.x); ay += bf2f(v.y); az += bf2f(v.z); aw += bf2f(v.w);
        }
    }
    int deg = nlo + nhi;
    float inv = 1.f / (float)(deg > 1 ? deg : 1);
    ushort4 o = make_ushort4(f2bf(ax * inv), f2bf(ay * inv), f2bf(az * inv), f2bf(aw * inv));
    *(ushort4*)(A + (size_t)node * KDIM + D + lane * 4) = o;   // re-read by GEMM: keep cached
}

// ---------------- MFMA GEMM: H(bf16) = relu(A @ Wb^T + b) ----------------
#define BM 64
#define BN 128
#define BK 32
#define LDK 40   // padded LDS k-stride (ushorts)

__global__ __launch_bounds__(256) void k_gemm(
    const ushort_t* __restrict__ A, const ushort_t* __restrict__ Wb,
    const float* __restrict__ bias, ushort_t* __restrict__ H) {
    __shared__ ushort_t As[BM][LDK];
    __shared__ ushort_t Bs[BN][LDK];

    int tid = threadIdx.x;
    int lane = tid & 63;
    int wave = tid >> 6;
    int wm = wave >> 1;   // 0..1: 32-row half
    int wn = wave & 1;    // 0..1: 64-col half
    int row0 = blockIdx.x * BM;
    int col0 = blockIdx.y * BN;

    f32x4 acc[2][4];
    #pragma unroll
    for (int i = 0; i < 2; ++i)
        #pragma unroll
        for (int j = 0; j < 4; ++j)
            acc[i][j] = (f32x4){0.f, 0.f, 0.f, 0.f};

    int r_a = tid >> 2;
    int kq = tid & 3;

    for (int kk = 0; kk < KDIM; kk += BK) {
        int ga = row0 + r_a; if (ga >= N_NODES) ga = N_NODES - 1;
        ushort4 a0 = *(const ushort4*)(A + (size_t)ga * KDIM + kk + kq * 8);
        ushort4 a1 = *(const ushort4*)(A + (size_t)ga * KDIM + kk + kq * 8 + 4);
        ushort4 b0 = *(const ushort4*)(Wb + (size_t)(col0 + r_a) * KDIM + kk + kq * 8);
        ushort4 b1 = *(const ushort4*)(Wb + (size_t)(col0 + r_a) * KDIM + kk + kq * 8 + 4);
        ushort4 b2 = *(const ushort4*)(Wb + (size_t)(col0 + r_a + 64) * KDIM + kk + kq * 8);
        ushort4 b3 = *(const ushort4*)(Wb + (size_t)(col0 + r_a + 64) * KDIM + kk + kq * 8 + 4);

        __syncthreads();
        *(ushort4*)&As[r_a][kq * 8]          = a0;
        *(ushort4*)&As[r_a][kq * 8 + 4]      = a1;
        *(ushort4*)&Bs[r_a][kq * 8]          = b0;
        *(ushort4*)&Bs[r_a][kq * 8 + 4]      = b1;
        *(ushort4*)&Bs[r_a + 64][kq * 8]     = b2;
        *(ushort4*)&Bs[r_a + 64][kq * 8 + 4] = b3;
        __syncthreads();

        int fr = lane & 15, fg = (lane >> 4) * 8;
        bf16x8 aF[2], bF[4];
        #pragma unroll
        for (int mf = 0; mf < 2; ++mf)
            aF[mf] = *(const bf16x8*)&As[wm * 32 + mf * 16 + fr][fg];
        #pragma unroll
        for (int nf = 0; nf < 4; ++nf)
            bF[nf] = *(const bf16x8*)&Bs[wn * 64 + nf * 16 + fr][fg];
        #pragma unroll
        for (int mf = 0; mf < 2; ++mf)
            #pragma unroll
            for (int nf = 0; nf < 4; ++nf)
                acc[mf][nf] = __builtin_amdgcn_mfma_f32_16x16x32_bf16(
                    aF[mf], bF[nf], acc[mf][nf], 0, 0, 0);
    }

    int fc = lane & 15, frow = (lane >> 4) * 4;
    #pragma unroll
    for (int nf = 0; nf < 4; ++nf) {
        int c = col0 + wn * 64 + nf * 16 + fc;
        float bc = bias[c];
        #pragma unroll
        for (int mf = 0; mf < 2; ++mf) {
            #pragma unroll
            for (int q = 0; q < 4; ++q) {
                int r = row0 + wm * 32 + mf * 16 + frow + q;
                if (r < N_NODES) {
                    float h = acc[mf][nf][q] + bc;
                    H[(size_t)r * D + c] = f2bf(h > 0.f ? h : 0.f);
                }
            }
        }
    }
}

// ---------------- edge diffs (two-sweep bf16 gather) -> scatter-mean -> tanh ----------------
__global__ void k_out(const ushort_t* __restrict__ H,
                      const int* __restrict__ curLo, const int* __restrict__ curHi,
                      const int* __restrict__ csr_col,
                      float* __restrict__ out) {
    int node = blockIdx.x * 4 + (threadIdx.x >> 6);
    int lane = threadIdx.x & 63;
    if (node >= N_NODES) return;
    ushort4 hb = *(const ushort4*)(H + (size_t)node * D + lane * 4);
    float hx = bf2f(hb.x), hy = bf2f(hb.y), hz = bf2f(hb.z), hw = bf2f(hb.w);
    int s0 = node * CAP;
    int nlo = curLo[node], nhi = curHi[node];
    float ax = 0.f, ay = 0.f, az = 0.f, aw = 0.f;
    #pragma unroll 1
    for (int half = 0; half < 2; ++half) {
        int s = half ? (s0 + CAP - nhi) : s0;
        int t = half ? (s0 + CAP) : (s0 + nlo);
        int e = s;
        for (; e + 4 <= t; e += 4) {
            int j0 = csr_col[e], j1 = csr_col[e + 1], j2 = csr_col[e + 2], j3 = csr_col[e + 3];
            ushort4 v0 = *(const ushort4*)(H + (size_t)j0 * D + lane * 4);
            ushort4 v1 = *(const ushort4*)(H + (size_t)j1 * D + lane * 4);
            ushort4 v2 = *(const ushort4*)(H + (size_t)j2 * D + lane * 4);
            ushort4 v3 = *(const ushort4*)(H + (size_t)j3 * D + lane * 4);
            float d;
            d = hx - bf2f(v0.x); ax += d * d;  d = hy - bf2f(v0.y); ay += d * d;
            d = hz - bf2f(v0.z); az += d * d;  d = hw - bf2f(v0.w); aw += d * d;
            d = hx - bf2f(v1.x); ax += d * d;  d = hy - bf2f(v1.y); ay += d * d;
            d = hz - bf2f(v1.z); az += d * d;  d = hw - bf2f(v1.w); aw += d * d;
            d = hx - bf2f(v2.x); ax += d * d;  d = hy - bf2f(v2.y); ay += d * d;
            d = hz - bf2f(v2.z); az += d * d;  d = hw - bf2f(v2.w); aw += d * d;
            d = hx - bf2f(v3.x); ax += d * d;  d = hy - bf2f(v3.y); ay += d * d;
            d = hz - bf2f(v3.z); az += d * d;  d = hw - bf2f(v3.w); aw += d * d;
        }
        for (; e < t; ++e) {
            int j = csr_col[e];
            ushort4 v = *(const ushort4*)(H + (size_t)j * D + lane * 4);
            float d;
            d = hx - bf2f(v.x); ax += d * d;  d = hy - bf2f(v.y); ay += d * d;
            d = hz - bf2f(v.z); az += d * d;  d = hw - bf2f(v.w); aw += d * d;
        }
    }
    int deg = nlo + nhi;
    float inv = 1.f / (float)(deg > 1 ? deg : 1);
    f32x4 o;
    o[0] = tanhf(ax * inv); o[1] = tanhf(ay * inv);
    o[2] = tanhf(az * inv); o[3] = tanhf(aw * inv);
    __builtin_nontemporal_store(o, (f32x4*)(out + (size_t)node * D + lane * 4));
}

// ---------------- launch ----------------

extern "C" void kernel_launch(void* const* d_in, const int* in_sizes, int n_in,
                              void* d_out, int out_size, void* d_ws, size_t ws_size,
                              hipStream_t stream) {
    const float* X    = (const float*)d_in[0];
    const int*   edge = (const int*)d_in[1];
    const float* Wr   = (const float*)d_in[2];
    const float* Wn   = (const float*)d_in[3];
    const float* bias = (const float*)d_in[4];
    float* out = (float*)d_out;

    char* ws = (char*)d_ws;
    size_t off = 0;
    auto alloc = [&](size_t bytes) -> void* {
        void* p = ws + off;
        off += (bytes + 255) & ~(size_t)255;
        return p;
    };
    int*      cursors = (int*)alloc(sizeof(int) * 2 * N_NODES);   // curLo | curHi
    int*      csr_col = (int*)alloc(sizeof(int) * N_NODES * CAP);
    ushort_t* A       = (ushort_t*)alloc(sizeof(ushort_t) * (size_t)N_NODES * KDIM);
    ushort_t* Wb      = (ushort_t*)alloc(sizeof(ushort_t) * (size_t)D * KDIM);
    ushort_t* H       = (ushort_t*)alloc(sizeof(ushort_t) * (size_t)N_NODES * D);

    int* curLo = cursors;
    int* curHi = cursors + N_NODES;
    const int* row = edge;
    const int* col = edge + N_EDGES;

    k_init<<<ZERO_BLOCKS + PREPW_BLOCKS + CASTX_BLOCKS, 256, 0, stream>>>(
        cursors, Wr, Wn, Wb, X, A);
    k_fill<<<(N_EDGES + 255) / 256, 256, 0, stream>>>(row, col, curLo, curHi,
                                                      csr_col, N_EDGES);
    k_mean<<<2500, 256, 0, stream>>>(curLo, curHi, csr_col, A);

    dim3 ggrid((N_NODES + BM - 1) / BM, D / BN);
    k_gemm<<<ggrid, 256, 0, stream>>>(A, Wb, bias, H);

    k_out<<<2500, 256, 0, stream>>>(H, curLo, curHi, csr_col, out);
}